// Round 1
// baseline (1544.755 us; speedup 1.0000x reference)
//
#include <hip/hip_runtime.h>

#define BB    32
#define TTOT  48
#define TT    24
#define NN    1000
#define FF    16
#define CCH   17      // F+1
#define HID   64
#define EMB   8
#define NHEADS 4
#define DDIM  16      // HID/HEADS
#define DEG   16

__device__ __forceinline__ float sigmoidf(float x) {
    return 1.0f / (1.0f + __expf(-x));
}

// dst[t][j] = bias[j] + sum_m src[t][m] * W[m][j], for t in {g, g+4, ..., g+20}
__device__ __forceinline__ void mm64(const float* __restrict__ W,
                                     const float* __restrict__ bias,
                                     const float (*__restrict__ src)[HID],
                                     float (*__restrict__ dst)[HID],
                                     int j, int g)
{
    float acc[6];
    const float bb = bias[j];
#pragma unroll
    for (int i = 0; i < 6; ++i) acc[i] = bb;
    for (int m = 0; m < HID; ++m) {
        const float w = W[m * HID + j];
#pragma unroll
        for (int i = 0; i < 6; ++i) acc[i] += src[g + 4 * i][m] * w;
    }
#pragma unroll
    for (int i = 0; i < 6; ++i) dst[g + 4 * i][j] = acc[i];
}

extern "C" __global__ __launch_bounds__(256)
void encoder_node(const float* __restrict__ X, const float* __restrict__ Y,
                  const int* __restrict__ esrc, const float* __restrict__ ew,
                  const float* __restrict__ pos,
                  const float* __restrict__ W_rel, const float* __restrict__ b_rel,
                  const float* __restrict__ W_root,
                  const float* __restrict__ W_fc, const float* __restrict__ b_fc,
                  const float* __restrict__ Wq, const float* __restrict__ bq,
                  const float* __restrict__ Wk, const float* __restrict__ bk,
                  const float* __restrict__ Wv, const float* __restrict__ bv,
                  const float* __restrict__ Wo, const float* __restrict__ bo,
                  const float* __restrict__ Wm, const float* __restrict__ bm,
                  float* __restrict__ out)
{
    // LDS carve-out (floats). Aliasing: ctx reuses h's slot, o0 reuses s's slot.
    __shared__ float buf[10800];          // 43200 B
    __shared__ float w_s[DEG];
    __shared__ int   src_s[DEG];

    float (*__restrict__ xn )[CCH] = (float(*)[CCH])(buf);          // 24x17
    float (*__restrict__ agg)[CCH] = (float(*)[CCH])(buf + 408);    // 24x17
    float (*__restrict__ h  )[HID] = (float(*)[HID])(buf + 816);    // 24x64
    float (*__restrict__ z  )[HID] = (float(*)[HID])(buf + 2352);   // 24x64
    float (*__restrict__ q  )[HID] = (float(*)[HID])(buf + 3888);   // 24x64
    float (*__restrict__ kk )[HID] = (float(*)[HID])(buf + 5424);   // 24x64
    float (*__restrict__ v  )[HID] = (float(*)[HID])(buf + 6960);   // 24x64
    float (*__restrict__ s  )[TT][TT] = (float(*)[TT][TT])(buf + 8496); // 4x24x24
    float (*__restrict__ ctx)[HID] = (float(*)[HID])(buf + 816);    // alias h
    float (*__restrict__ o0 )[HID] = (float(*)[HID])(buf + 8496);   // alias s

    const int u   = blockIdx.x;           // node id in [0, B*N)
    const int b   = u / NN;
    const int n   = u - b * NN;
    const int tid = threadIdx.x;

    if (tid < DEG) {
        src_s[tid] = esrc[u * DEG + tid];
        w_s[tid]   = ew[u * DEG + tid];
    }
    // own feature row: xn[t][0]=y, xn[t][1+f]=X
    for (int e = tid; e < TT * CCH; e += 256) {
        const int t = e / CCH, c = e - t * CCH;
        buf[e] = (c == 0) ? Y[(b * TTOT + t) * NN + n]
                          : X[((size_t)(b * TTOT + t) * NN + n) * FF + (c - 1)];
    }
    __syncthreads();

    // weighted neighbor aggregation: agg[t][c] = sum_k w_k * x_nodes[src_k][t][c]
    for (int e = tid; e < TT * CCH; e += 256) {
        const int t = e / CCH, c = e - t * CCH;
        float a = 0.f;
#pragma unroll
        for (int kE = 0; kE < DEG; ++kE) {
            const int ns = src_s[kE] - b * NN;   // src is within same batch block
            const float xv = (c == 0)
                ? Y[(b * TTOT + t) * NN + ns]
                : X[((size_t)(b * TTOT + t) * NN + ns) * FF + (c - 1)];
            a += w_s[kE] * xv;
        }
        agg[t][c] = a;
    }
    __syncthreads();

    const int j = tid & 63;
    const int g = tid >> 6;   // 0..3; rows g, g+4, ..., g+20

    // h = sigmoid(agg @ W_rel + b_rel + xn @ W_root)
    {
        float acc[6];
        const float br = b_rel[j];
#pragma unroll
        for (int i = 0; i < 6; ++i) acc[i] = br;
        for (int c = 0; c < CCH; ++c) {
            const float wr = W_rel[c * HID + j];
            const float wt = W_root[c * HID + j];
#pragma unroll
            for (int i = 0; i < 6; ++i) {
                const int t = g + 4 * i;
                acc[i] += agg[t][c] * wr + xn[t][c] * wt;
            }
        }
#pragma unroll
        for (int i = 0; i < 6; ++i) h[g + 4 * i][j] = sigmoidf(acc[i]);
    }
    __syncthreads();

    // z = concat(pos, h, X, y) @ W_fc + b_fc   (rows: 0..7 pos, 8..71 h, 72..87 X, 88 y)
    {
        float acc[6];
        const float bf = b_fc[j];
#pragma unroll
        for (int i = 0; i < 6; ++i) acc[i] = bf;
        for (int e2 = 0; e2 < EMB; ++e2) {
            const float w = W_fc[e2 * HID + j];
#pragma unroll
            for (int i = 0; i < 6; ++i) acc[i] += pos[(g + 4 * i) * EMB + e2] * w;
        }
        for (int m = 0; m < HID; ++m) {
            const float w = W_fc[(EMB + m) * HID + j];
#pragma unroll
            for (int i = 0; i < 6; ++i) acc[i] += h[g + 4 * i][m] * w;
        }
        for (int f = 0; f < FF; ++f) {
            const float w = W_fc[(EMB + HID + f) * HID + j];
#pragma unroll
            for (int i = 0; i < 6; ++i) acc[i] += xn[g + 4 * i][1 + f] * w;
        }
        {
            const float w = W_fc[(EMB + HID + FF) * HID + j];
#pragma unroll
            for (int i = 0; i < 6; ++i) acc[i] += xn[g + 4 * i][0] * w;
        }
#pragma unroll
        for (int i = 0; i < 6; ++i) z[g + 4 * i][j] = acc[i];
    }
    __syncthreads();

    // q, k, v
    mm64(Wq, bq, z, q,  j, g);
    mm64(Wk, bk, z, kk, j, g);
    mm64(Wv, bv, z, v,  j, g);
    __syncthreads();

    // scores s[hh][r][c2] = (q[r]·k[c2])_head / 4
    for (int e = tid; e < NHEADS * TT * TT; e += 256) {
        const int hh = e / (TT * TT);
        const int r  = (e / TT) % TT;
        const int c2 = e % TT;
        float a = 0.f;
#pragma unroll
        for (int d = 0; d < DDIM; ++d) a += q[r][hh * DDIM + d] * kk[c2][hh * DDIM + d];
        s[hh][r][c2] = a * 0.25f;
    }
    __syncthreads();

    // softmax over last dim (96 rows, one thread each)
    if (tid < NHEADS * TT) {
        const int hh = tid / TT, r = tid - hh * TT;
        float* row = s[hh][r];
        float mx = row[0];
        for (int i2 = 1; i2 < TT; ++i2) mx = fmaxf(mx, row[i2]);
        float sm = 0.f;
        for (int i2 = 0; i2 < TT; ++i2) { const float ev = __expf(row[i2] - mx); row[i2] = ev; sm += ev; }
        const float inv = 1.f / sm;
        for (int i2 = 0; i2 < TT; ++i2) row[i2] *= inv;
    }
    __syncthreads();

    // ctx[t][j] = sum_jj s[hh][t][jj] * v[jj][j]    (hh = j>>4)
    {
        const int hh = j >> 4;
        float acc[6];
#pragma unroll
        for (int i = 0; i < 6; ++i) acc[i] = 0.f;
        for (int jj = 0; jj < TT; ++jj) {
            const float vv = v[jj][j];
#pragma unroll
            for (int i = 0; i < 6; ++i) acc[i] += s[hh][g + 4 * i][jj] * vv;
        }
#pragma unroll
        for (int i = 0; i < 6; ++i) ctx[g + 4 * i][j] = acc[i];
    }
    __syncthreads();

    // o0 = ctx @ Wo + bo   (o0 aliases s — s dead now)
    mm64(Wo, bo, ctx, o0, j, g);
    __syncthreads();

    // out[b][t][n][:] = o0 @ W_mlp + b_mlp
    {
        float acc[6];
        const float bb2 = bm[j];
#pragma unroll
        for (int i = 0; i < 6; ++i) acc[i] = bb2;
        for (int m = 0; m < HID; ++m) {
            const float w = Wm[m * HID + j];
#pragma unroll
            for (int i = 0; i < 6; ++i) acc[i] += o0[g + 4 * i][m] * w;
        }
#pragma unroll
        for (int i = 0; i < 6; ++i) {
            const int t = g + 4 * i;
            out[((size_t)(b * TT + t) * NN + n) * HID + j] = acc[i];
        }
    }
}

extern "C" void kernel_launch(void* const* d_in, const int* in_sizes, int n_in,
                              void* d_out, int out_size, void* d_ws, size_t ws_size,
                              hipStream_t stream)
{
    const float* X     = (const float*)d_in[0];
    const float* Y     = (const float*)d_in[1];
    const int*   esrc  = (const int*)d_in[2];
    // d_in[3] = edge_dst: structure is known (dst = u*DEG+k), unused
    const float* ew    = (const float*)d_in[4];
    const float* pos   = (const float*)d_in[5];
    const float* W_rel = (const float*)d_in[6];
    const float* b_rel = (const float*)d_in[7];
    const float* W_root= (const float*)d_in[8];
    const float* W_fc  = (const float*)d_in[9];
    const float* b_fc  = (const float*)d_in[10];
    const float* Wq    = (const float*)d_in[11];
    const float* bq    = (const float*)d_in[12];
    const float* Wk    = (const float*)d_in[13];
    const float* bk    = (const float*)d_in[14];
    const float* Wv    = (const float*)d_in[15];
    const float* bv    = (const float*)d_in[16];
    const float* Wo    = (const float*)d_in[17];
    const float* bo    = (const float*)d_in[18];
    const float* Wm    = (const float*)d_in[19];
    const float* bm    = (const float*)d_in[20];
    float* out = (float*)d_out;

    encoder_node<<<dim3(BB * NN), dim3(256), 0, stream>>>(
        X, Y, esrc, ew, pos, W_rel, b_rel, W_root, W_fc, b_fc,
        Wq, bq, Wk, bk, Wv, bv, Wo, bo, Wm, bm, out);
}